// Round 26
// baseline (346.082 us; speedup 1.0000x reference)
//
#include <hip/hip_runtime.h>
#include <hip/hip_bf16.h>

typedef unsigned short u16;
typedef short s16x8 __attribute__((ext_vector_type(8)));
typedef short s16x4 __attribute__((ext_vector_type(4)));
typedef float f32x4 __attribute__((ext_vector_type(4)));

#define SEQ   2048
#define BATCH 2
#define NHEAD 16

__device__ __forceinline__ float b2f(u16 u) {
    unsigned x = ((unsigned)u) << 16;
    return __builtin_bit_cast(float, x);
}
__device__ __forceinline__ u16 f2b(float f) {
    unsigned x = __builtin_bit_cast(unsigned, f);
    unsigned r = (x + 0x7fffu + ((x >> 16) & 1u)) >> 16;
    return (u16)r;
}
__device__ __forceinline__ u16 f2b_hw(float f) {
    return __builtin_bit_cast(u16, __float2bfloat16(f));
}
__device__ __forceinline__ s16x8 comb(s16x4 lo, s16x4 hi) {
    return __builtin_shufflevector(lo, hi, 0, 1, 2, 3, 4, 5, 6, 7);
}
__device__ __forceinline__ void gload16(const void* g, void* l) {
    __builtin_amdgcn_global_load_lds(
        (const __attribute__((address_space(1))) void*)g,
        (__attribute__((address_space(3))) void*)l, 16, 0, 0);
}

// ---------------------------------------------------------------------------
// Fused f32->bf16 convert for 4 regions (x, Wqd, Wkvd, Wqu).  (R24 layout —
// Wkvu is converted separately into the qlat slot AFTER qup; R25's merged
// cvt5 + kvup-first reorder clobbered wqu_bf inside the knv slot.)
// ---------------------------------------------------------------------------
__global__ __launch_bounds__(256) void cvt4_k(
    const float* __restrict__ x, const float* __restrict__ wqd,
    const float* __restrict__ wkvd, const float* __restrict__ wqu,
    u16* __restrict__ xb, u16* __restrict__ wqdb,
    u16* __restrict__ wkvdb, u16* __restrict__ wqub)
{
    const int total = 4358144;
    int i = blockIdx.x * 256 + threadIdx.x;
    const int stride = gridDim.x * 256;
    for (; i < total; i += stride) {
        const float4* src; ushort4* dst; int off;
        if (i < 2097152)      { src = (const float4*)x;    dst = (ushort4*)xb;    off = i; }
        else if (i < 2883584) { src = (const float4*)wqd;  dst = (ushort4*)wqdb;  off = i - 2097152; }
        else if (i < 3178496) { src = (const float4*)wkvd; dst = (ushort4*)wkvdb; off = i - 2883584; }
        else                  { src = (const float4*)wqu;  dst = (ushort4*)wqub;  off = i - 3178496; }
        float4 v = src[off];
        ushort4 o = { f2b(v.x), f2b(v.y), f2b(v.z), f2b(v.w) };
        dst[off] = o;
    }
}

__global__ __launch_bounds__(256) void cvt_bf16_k(
    const float* __restrict__ in, u16* __restrict__ out, int n4)
{
    int i = blockIdx.x * 256 + threadIdx.x;
    const int stride = gridDim.x * 256;
    for (; i < n4; i += stride) {
        float4 v = ((const float4*)in)[i];
        ushort4 o = { f2b(v.x), f2b(v.y), f2b(v.z), f2b(v.w) };
        ((ushort4*)out)[i] = o;
    }
}

// ---------------------------------------------------------------------------
// 8-phase GEMM (T2+T3+T4+T5), verified R20-R24. TM=256 or 128. bf16 A.
// MODE: 0 bf16-out | 1 f32-out | 2 qup(rope+QS) | 3 down(dual-dest)
// ---------------------------------------------------------------------------
template <int MODE, int TM>
__global__ __launch_bounds__(512, 2) void gemm8p_k(
    const u16* __restrict__ A, const u16* __restrict__ W0,
    const u16* __restrict__ W1, const float* __restrict__ b0,
    const float* __restrict__ b1, void* __restrict__ C0, void* __restrict__ C1,
    int N, int K, int lda,
    const float* __restrict__ fc, const float* __restrict__ fs)
{
    constexpr int AH  = TM / 128;
    constexpr int MPP = TM == 256 ? 2 : 1;
    __shared__ u16 lsA[2][AH][128 * 64];
    __shared__ u16 lsB[2][2][128 * 64];
    const int tid  = threadIdx.x;
    const int lane = tid & 63;
    const int w    = tid >> 6;
    const int wm   = w >> 2;
    const int wn   = w & 3;
    const int row0 = blockIdx.y * TM;
    const int col0 = blockIdx.x * 256;
    const int nt   = K / 64;

    auto stageA = [&](int t, int h) {
        const int kt = t * 64, buf = t & 1;
#pragma unroll
        for (int j = 0; j < 2; j++) {
            const int g = (w * 2 + j) * 64 + lane;
            const int row = g >> 3, c16 = g & 7;
            const int cs = c16 ^ (row & 7);
            gload16(A + (size_t)(row0 + h * 128 + row) * lda + kt + cs * 8,
                    &lsA[buf][h][(w * 2 + j) * 512]);
        }
    };
    auto stageB = [&](int t, int h) {
        const int kt = t * 64, buf = t & 1;
#pragma unroll
        for (int j = 0; j < 2; j++) {
            const int g = (w * 2 + j) * 64 + lane;
            const int row = g >> 3, c16 = g & 7;
            const int cs = c16 ^ (row & 7);
            int rw = col0 + h * 128 + row;
            const u16* Wp;
            if (MODE == 3) {
                const bool in1 = rw >= 1536;
                int r2 = in1 ? rw - 1536 : rw;
                if (in1 && r2 > 575) r2 = 575;
                Wp = (in1 ? W1 : W0) + (size_t)r2 * K;
            } else {
                if (rw >= N) rw = N - 1;
                Wp = W0 + (size_t)rw * K;
            }
            gload16(Wp + kt + cs * 8, &lsB[buf][h][(w * 2 + j) * 512]);
        }
    };
    auto readA = [&](int buf, int mf, int kh) -> s16x8 {
        const int h  = TM == 256 ? wm : 0;
        const int ra = (TM == 256 ? mf * 16 : wm * 64 + mf * 16) + (lane & 15);
        const int c16 = kh * 4 + (lane >> 4);
        return *(const s16x8*)&lsA[buf][h][(ra * 8 + (c16 ^ (ra & 7))) * 8];
    };
    auto readB = [&](int buf, int nf, int kh) -> s16x8 {
        const int rb = (wn & 1) * 64 + nf * 16 + (lane & 15);
        const int c16 = kh * 4 + (lane >> 4);
        return *(const s16x8*)&lsB[buf][wn >> 1][(rb * 8 + (c16 ^ (rb & 7))) * 8];
    };

    f32x4 acc[4 * MPP][4];
#pragma unroll
    for (int i = 0; i < 4 * MPP; i++)
#pragma unroll
        for (int j = 0; j < 4; j++) acc[i][j] = (f32x4){0.f, 0.f, 0.f, 0.f};

    stageB(0, 0); stageB(0, 1);
#pragma unroll
    for (int h = 0; h < AH; h++) stageA(0, h);
    stageB(1, 0); stageB(1, 1);
    asm volatile("s_waitcnt vmcnt(4)" ::: "memory");
    asm volatile("s_barrier" ::: "memory");

    for (int t = 0; t < nt; t++) {
        const int buf = t & 1;
        s16x8 bfr[4][2];
#pragma unroll
        for (int nf = 0; nf < 4; nf++)
#pragma unroll
            for (int kh = 0; kh < 2; kh++) bfr[nf][kh] = readB(buf, nf, kh);
#pragma unroll
        for (int ph = 0; ph < 4; ph++) {
            s16x8 af[MPP][2];
#pragma unroll
            for (int m2 = 0; m2 < MPP; m2++)
#pragma unroll
                for (int kh = 0; kh < 2; kh++)
                    af[m2][kh] = readA(buf, ph * MPP + m2, kh);
            if (ph == 0) { if (t + 1 < nt) stageA(t + 1, 0); }
            else if (ph == 1) {
                if (TM == 256) { if (t + 1 < nt) stageA(t + 1, 1); }
                if (t + 2 < nt) stageB(t + 2, 0);
            } else if (ph == 2) { if (t + 2 < nt) stageB(t + 2, 1); }
            __builtin_amdgcn_s_setprio(1);
#pragma unroll
            for (int kh = 0; kh < 2; kh++)
#pragma unroll
                for (int m2 = 0; m2 < MPP; m2++)
#pragma unroll
                    for (int nf = 0; nf < 4; nf++)
                        acc[ph * MPP + m2][nf] = __builtin_amdgcn_mfma_f32_16x16x32_bf16(
                            af[m2][kh], bfr[nf][kh], acc[ph * MPP + m2][nf], 0, 0, 0);
            __builtin_amdgcn_s_setprio(0);
            if (ph == 0) asm volatile("s_barrier" ::: "memory");
        }
        if (t + 2 < nt) asm volatile("s_waitcnt vmcnt(4)" ::: "memory");
        else            asm volatile("s_waitcnt vmcnt(0)" ::: "memory");
        asm volatile("s_barrier" ::: "memory");
    }

    const float QS = 0.10411754f;  // 192^-0.5 * log2(e)
    const int rbase = row0 + wm * (TM == 256 ? 128 : 64) + ((lane >> 4) << 2);
    const int cbase = col0 + wn * 64 + (lane & 15);
#pragma unroll
    for (int nf = 0; nf < 4; nf++) {
        const int col = cbase + nf * 16;
        if (MODE == 3) {
            if (col < 2112) {
                const bool c1 = col >= 1536;
                const float bv = c1 ? b1[col - 1536] : b0[col];
#pragma unroll
                for (int mf = 0; mf < 4 * MPP; mf++)
#pragma unroll
                    for (int r = 0; r < 4; r++) {
                        const int row = rbase + mf * 16 + r;
                        const float v = acc[mf][nf][r] + bv;
                        if (c1) ((u16*)C1)[(size_t)row * 576 + col - 1536] = f2b_hw(v);
                        else    ((u16*)C0)[(size_t)row * 1536 + col] = f2b_hw(v);
                    }
            }
        } else if (MODE == 2) {
            const float bv = b0[col];
            const int colBase = col0 + wn * 64 + nf * 16;
            const int dh0 = colBase % 192;
            const bool ropeBlk = (dh0 >= 128);
            const int ib = (dh0 - 128 + (lane & 15)) >> 1;
#pragma unroll
            for (int mf = 0; mf < 4 * MPP; mf++)
#pragma unroll
                for (int r = 0; r < 4; r++) {
                    const int row = rbase + mf * 16 + r;
                    float v = acc[mf][nf][r] + bv;
                    if (ropeBlk) {
                        const float pp = __shfl_xor(v, 1);
                        const int s = row & (SEQ - 1);
                        const float c = fc[s * 32 + ib], sn = fs[s * 32 + ib];
                        v = (lane & 1) ? (v * c + pp * sn) : (v * c - pp * sn);
                    }
                    ((u16*)C0)[(size_t)row * 3072 + col] = f2b_hw(v * QS);
                }
        } else {
            if (col < N) {
                const float bv = b0[col];
#pragma unroll
                for (int mf = 0; mf < 4 * MPP; mf++)
#pragma unroll
                    for (int r = 0; r < 4; r++) {
                        const int row = rbase + mf * 16 + r;
                        const float v = acc[mf][nf][r] + bv;
                        if (MODE == 1) ((float*)C0)[(size_t)row * N + col] = v;
                        else           ((u16*)C0)[(size_t)row * N + col] = f2b_hw(v);
                    }
            }
        }
    }
}

// ---------------------------------------------------------------------------
// Merged RMSNorm (qlat + kvb) + rope_k — vectorized.
// ---------------------------------------------------------------------------
__global__ __launch_bounds__(256) void norm_rope_k(
    u16* __restrict__ qlat, u16* __restrict__ kvb,
    const float* __restrict__ qnw, const float* __restrict__ kvnw,
    const float* __restrict__ fc, const float* __restrict__ fs,
    u16* __restrict__ krope)
{
    const int bid = blockIdx.x;
    const int row = bid & 4095;
    const bool isq = bid < 4096;
    u16* xr = isq ? qlat + (size_t)row * 1536 : kvb + (size_t)row * 576;
    const int cols = isq ? 1536 : 512;
    const float* wv = isq ? qnw : kvnw;
    const int t = threadIdx.x;
    const int nv = cols >> 3;

    if (!isq && t < 32) {
        const int i = t;
        const int s = row & (SEQ - 1);
        const u16* src = kvb + (size_t)row * 576 + 512 + 2 * i;
        const float xr0 = b2f(src[0]), xi0 = b2f(src[1]);
        const float c = fc[s * 32 + i], sn = fs[s * 32 + i];
        ushort2 o;
        o.x = f2b(xr0 * c - xi0 * sn);
        o.y = f2b(xr0 * sn + xi0 * c);
        *((ushort2*)(krope + (size_t)row * 64) + i) = o;
    }

    s16x8 v = {0,0,0,0,0,0,0,0};
    float ss = 0.f;
    if (t < nv) {
        v = *(const s16x8*)(xr + t * 8);
#pragma unroll
        for (int e = 0; e < 8; e++) { float f = b2f((u16)v[e]); ss += f * f; }
    }
#pragma unroll
    for (int off = 32; off; off >>= 1) ss += __shfl_xor(ss, off);
    __shared__ float red[4];
    if ((t & 63) == 0) red[t >> 6] = ss;
    __syncthreads();
    const float tot = red[0] + red[1] + red[2] + red[3];
    const float inv = rsqrtf(tot / (float)cols + 1.1920929e-7f);
    if (t < nv) {
        s16x8 o;
#pragma unroll
        for (int e = 0; e < 8; e++)
            o[e] = (short)f2b(b2f((u16)v[e]) * inv * wv[t * 8 + e]);
        *(s16x8*)(xr + t * 8) = o;
    }
}

// ---------------------------------------------------------------------------
// MFMA flash attention v12: v11 + T5 setprio on MFMA clusters + prefetch
// issued before the staging barrier (both correctness-neutral).
// ---------------------------------------------------------------------------
__global__ __launch_bounds__(256, 2) void attn_k(
    const u16* __restrict__ Q, const u16* __restrict__ KNV,
    const u16* __restrict__ KR, u16* __restrict__ O)
{
    __shared__ u16 k_lds[64][204];
    __shared__ u16 v_t[128][76];

    const int tid  = threadIdx.x;
    const int lane = tid & 63;
    const int w    = tid >> 6;
    const int lr   = lane & 15;
    const int lq   = lane >> 4;

    const int bid = blockIdx.x;
    const int qt  = (bid < 256) ? (15 - (bid >> 5)) : ((bid - 256) >> 5);
    const int bh  = bid & 31;
    const int h   = bh & 15;
    const int b   = bh >> 4;
    const int q0  = qt * 128;
    const int bS  = b * SEQ;

    s16x8 qf[2][6];
#pragma unroll
    for (int mb = 0; mb < 2; mb++) {
        const u16* qp = Q + (size_t)(bS + q0 + w * 32 + mb * 16 + lr) * 3072
                        + h * 192 + (lq << 2);
#pragma unroll
        for (int kc = 0; kc < 6; kc++)
            qf[mb][kc] = comb(*(const s16x4*)(qp + kc * 32),
                              *(const s16x4*)(qp + kc * 32 + 16));
    }

    f32x4 o_acc[2][8];
#pragma unroll
    for (int mb = 0; mb < 2; mb++)
#pragma unroll
        for (int d = 0; d < 8; d++) o_acc[mb][d] = (f32x4){0.f, 0.f, 0.f, 0.f};
    float m_run[2] = { -1e30f, -1e30f };
    float l_run[2] = { 0.f, 0.f };

    const int ntiles = (q0 + 128) / 64;
    const int qmax_w = q0 + w * 32 + 31;

    s16x8 kr[6], vr[4];
    const int kkey = tid >> 2;
    const int ka   = tid & 3;

    {
        const u16* kn  = KNV + (size_t)(bS + kkey) * 4096 + h * 256;
        const u16* krp = KR + (size_t)(bS + kkey) * 64;
#pragma unroll
        for (int i = 0; i < 6; i++) {
            const int col = ka * 48 + i * 8;
            kr[i] = *(const s16x8*)(col < 128 ? kn + col : krp + (col - 128));
        }
#pragma unroll
        for (int i = 0; i < 4; i++) {
            const int idx = tid + i * 256;
            vr[i] = *(const s16x8*)(KNV + (size_t)(bS + (idx >> 4)) * 4096
                                    + h * 256 + 128 + (idx & 15) * 8);
        }
    }

    for (int t = 0; t < ntiles; t++) {
        // store staged regs -> LDS
#pragma unroll
        for (int i = 0; i < 6; i++) {
            const int c0 = ka * 48 + i * 8;
            *(s16x4*)&k_lds[kkey][c0]     = __builtin_shufflevector(kr[i], kr[i], 0, 1, 2, 3);
            *(s16x4*)&k_lds[kkey][c0 + 4] = __builtin_shufflevector(kr[i], kr[i], 4, 5, 6, 7);
        }
#pragma unroll
        for (int i = 0; i < 4; i++) {
            const int idx = tid + i * 256;
            const int key = idx >> 4, d0 = (idx & 15) * 8;
            const int xw = (d0 >> 4) << 2;
#pragma unroll
            for (int e = 0; e < 8; e++) v_t[d0 + e][key ^ xw] = (u16)vr[i][e];
        }
        // issue next tile's prefetch BEFORE the barrier (no LDS dependency)
        if (t + 1 < ntiles) {
            const int nk = (t + 1) * 64;
            const u16* kn  = KNV + (size_t)(bS + nk + kkey) * 4096 + h * 256;
            const u16* krp = KR + (size_t)(bS + nk + kkey) * 64;
#pragma unroll
            for (int i = 0; i < 6; i++) {
                const int col = ka * 48 + i * 8;
                kr[i] = *(const s16x8*)(col < 128 ? kn + col : krp + (col - 128));
            }
#pragma unroll
            for (int i = 0; i < 4; i++) {
                const int idx = tid + i * 256;
                vr[i] = *(const s16x8*)(KNV + (size_t)(bS + nk + (idx >> 4)) * 4096
                                        + h * 256 + 128 + (idx & 15) * 8);
            }
        }
        __syncthreads();

        const int kt0 = t * 64;
        if (kt0 <= qmax_w) {
            f32x4 sa[2][4];
#pragma unroll
            for (int mb = 0; mb < 2; mb++)
#pragma unroll
                for (int f = 0; f < 4; f++) sa[mb][f] = (f32x4){0.f, 0.f, 0.f, 0.f};
            __builtin_amdgcn_s_setprio(1);
#pragma unroll
            for (int kc = 0; kc < 6; kc++) {
                const int kb = kc * 32 + (lq << 2);
#pragma unroll
                for (int f = 0; f < 4; f++) {
                    s16x8 kf = comb(*(const s16x4*)&k_lds[f * 16 + lr][kb],
                                    *(const s16x4*)&k_lds[f * 16 + lr][kb + 16]);
                    sa[0][f] = __builtin_amdgcn_mfma_f32_16x16x32_bf16(kf, qf[0][kc], sa[0][f], 0, 0, 0);
                    sa[1][f] = __builtin_amdgcn_mfma_f32_16x16x32_bf16(kf, qf[1][kc], sa[1][f], 0, 0, 0);
                }
            }
            __builtin_amdgcn_s_setprio(0);

            s16x8 pb[2][2];
#pragma unroll
            for (int mb = 0; mb < 2; mb++) {
                const int qrow = q0 + w * 32 + mb * 16 + lr;
                const bool need_mask = (kt0 + 63 > qrow);
                float p[4][4];
#pragma unroll
                for (int f = 0; f < 4; f++)
#pragma unroll
                    for (int r = 0; r < 4; r++) {
                        float s = sa[mb][f][r];
                        if (need_mask && (kt0 + f * 16 + lq * 4 + r > qrow)) s = -1e30f;
                        p[f][r] = s;
                    }
                float tm = p[0][0];
#pragma unroll
                for (int f = 0; f < 4; f++)
#pragma unroll
                    for (int r = 0; r < 4; r++) tm = fmaxf(tm, p[f][r]);
                tm = fmaxf(tm, __shfl_xor(tm, 16));
                tm = fmaxf(tm, __shfl_xor(tm, 32));

                const float mo = m_run[mb];
                const bool keep = __all(tm <= mo + 8.f);
                float corr = 1.f;
                if (!keep) {
                    const float nm = fmaxf(mo, tm);
                    corr = __builtin_amdgcn_exp2f(mo - nm);
                    m_run[mb] = nm;
                }
                const float mbase = m_run[mb];
#pragma unroll
                for (int f = 0; f < 4; f++)
#pragma unroll
                    for (int r = 0; r < 4; r++)
                        p[f][r] = __builtin_amdgcn_exp2f(p[f][r] - mbase);
                float ps = 0.f;
#pragma unroll
                for (int f = 0; f < 4; f++)
#pragma unroll
                    for (int r = 0; r < 4; r++) ps += p[f][r];
                ps += __shfl_xor(ps, 16);
                ps += __shfl_xor(ps, 32);
                l_run[mb] = l_run[mb] * corr + ps;
                if (!keep) {
#pragma unroll
                    for (int d = 0; d < 8; d++)
#pragma unroll
                        for (int r = 0; r < 4; r++) o_acc[mb][d][r] *= corr;
                }
#pragma unroll
                for (int hf = 0; hf < 2; hf++) {
                    s16x8 v;
#pragma unroll
                    for (int j = 0; j < 8; j++)
                        v[j] = (short)f2b_hw(p[hf * 2 + (j >> 2)][j & 3]);
                    pb[mb][hf] = v;
                }
            }

            __builtin_amdgcn_s_setprio(1);
#pragma unroll
            for (int hf = 0; hf < 2; hf++) {
                const int pc = hf * 32 + (lq << 2);
#pragma unroll
                for (int df = 0; df < 8; df++) {
                    const int row = df * 16 + lr;
                    const int xr0 = df << 2;
                    s16x8 vf = comb(*(const s16x4*)&v_t[row][pc ^ xr0],
                                    *(const s16x4*)&v_t[row][(pc + 16) ^ xr0]);
                    o_acc[0][df] = __builtin_amdgcn_mfma_f32_16x16x32_bf16(vf, pb[0][hf], o_acc[0][df], 0, 0, 0);
                    o_acc[1][df] = __builtin_amdgcn_mfma_f32_16x16x32_bf16(vf, pb[1][hf], o_acc[1][df], 0, 0, 0);
                }
            }
            __builtin_amdgcn_s_setprio(0);
        }
        __syncthreads();
    }

#pragma unroll
    for (int mb = 0; mb < 2; mb++) {
        const float invl = 1.f / l_run[mb];
        u16* op = O + (size_t)(bS + q0 + w * 32 + mb * 16 + lr) * 2048 + h * 128 + lq * 4;
#pragma unroll
        for (int df = 0; df < 8; df++) {
            ushort4 ov = { f2b_hw(o_acc[mb][df][0] * invl), f2b_hw(o_acc[mb][df][1] * invl),
                           f2b_hw(o_acc[mb][df][2] * invl), f2b_hw(o_acc[mb][df][3] * invl) };
            *(ushort4*)(op + df * 16) = ov;
        }
    }
}

// ---------------------------------------------------------------------------
extern "C" void kernel_launch(void* const* d_in, const int* in_sizes, int n_in,
                              void* d_out, int out_size, void* d_ws, size_t ws_size,
                              hipStream_t stream)
{
    const float* x    = (const float*)d_in[0];
    const float* fc   = (const float*)d_in[1];
    const float* fs   = (const float*)d_in[2];
    const float* Wqd  = (const float*)d_in[3];
    const float* bqd  = (const float*)d_in[4];
    const float* qnw  = (const float*)d_in[5];
    const float* Wqu  = (const float*)d_in[6];
    const float* bqu  = (const float*)d_in[7];
    const float* Wkvd = (const float*)d_in[8];
    const float* bkvd = (const float*)d_in[9];
    const float* kvnw = (const float*)d_in[10];
    const float* Wkvu = (const float*)d_in[11];
    const float* bkvu = (const float*)d_in[12];
    const float* Wo   = (const float*)d_in[13];
    const float* bo   = (const float*)d_in[14];

    char* ws = (char*)d_ws;
    // Lifetime-audited layout (R24, proven):
    u16* kvb     = (u16*)(ws);                 // [4096][576]  live: down..kvup
    u16* qlat    = (u16*)(ws + 4718592);       // [4096][1536] live: down..qup
    u16* qbuf    = (u16*)(ws + 17301504);      // [4096][3072] live: qup..attn
    u16* krope   = (u16*)(ws + 42467328);      // [4096][64]   live: norm..attn
    u16* knv     = (u16*)(ws + 42991616);      // [4096][4096] live: kvup..attn
    u16* attn_o  = (u16*)(ws);                 // [4096][2048] live: attn..out (over kvb+qlat)
    u16* x_bf    = (u16*)(ws + 17301504);      // in qbuf slot, dead before qup
    u16* wqd_bf  = (u16*)(ws + 42991616);      // in knv slot, dead before kvup
    u16* wkvd_bf = (u16*)(ws + 49283072);      //   "
    u16* wqu_bf  = (u16*)(ws + 51642368);      //   "  (qup runs BEFORE kvup)
    u16* wkvu_bf = (u16*)(ws + 4718592);       // in qlat slot, converted after qup
    u16* wo_bf   = (u16*)(ws + 42991616);      // in knv slot, knv dead after attn

    cvt4_k<<<2048, 256, 0, stream>>>(x, Wqd, Wkvd, Wqu, x_bf, wqd_bf, wkvd_bf, wqu_bf);
    gemm8p_k<3, 256><<<dim3(9, 16), 512, 0, stream>>>(
        x_bf, wqd_bf, wkvd_bf, bqd, bkvd, qlat, kvb, 2112, 2048, 2048, nullptr, nullptr);
    norm_rope_k<<<8192, 256, 0, stream>>>(qlat, kvb, qnw, kvnw, fc, fs, krope);
    gemm8p_k<2, 256><<<dim3(12, 16), 512, 0, stream>>>(
        qlat, wqu_bf, nullptr, bqu, nullptr, qbuf, nullptr, 3072, 1536, 1536, fc, fs);
    cvt_bf16_k<<<1024, 256, 0, stream>>>(Wkvu, wkvu_bf, 2097152 / 4);
    gemm8p_k<0, 256><<<dim3(16, 16), 512, 0, stream>>>(
        kvb, wkvu_bf, nullptr, bkvu, nullptr, knv, nullptr, 4096, 512, 576, nullptr, nullptr);
    attn_k<<<512, 256, 0, stream>>>(qbuf, knv, krope, attn_o);
    cvt_bf16_k<<<1024, 256, 0, stream>>>(Wo, wo_bf, 4194304 / 4);
    gemm8p_k<1, 128><<<dim3(8, 32), 512, 0, stream>>>(
        attn_o, wo_bf, nullptr, bo, nullptr, d_out, nullptr, 2048, 2048, 2048, nullptr, nullptr);
}

// Round 27
// 338.566 us; speedup vs baseline: 1.0222x; 1.0222x over previous
//
#include <hip/hip_runtime.h>
#include <hip/hip_bf16.h>

typedef unsigned short u16;
typedef short s16x8 __attribute__((ext_vector_type(8)));
typedef short s16x4 __attribute__((ext_vector_type(4)));
typedef float f32x4 __attribute__((ext_vector_type(4)));

#define SEQ   2048
#define BATCH 2
#define NHEAD 16

__device__ __forceinline__ float b2f(u16 u) {
    unsigned x = ((unsigned)u) << 16;
    return __builtin_bit_cast(float, x);
}
__device__ __forceinline__ u16 f2b(float f) {
    unsigned x = __builtin_bit_cast(unsigned, f);
    unsigned r = (x + 0x7fffu + ((x >> 16) & 1u)) >> 16;
    return (u16)r;
}
__device__ __forceinline__ u16 f2b_hw(float f) {
    return __builtin_bit_cast(u16, __float2bfloat16(f));
}
__device__ __forceinline__ s16x8 comb(s16x4 lo, s16x4 hi) {
    return __builtin_shufflevector(lo, hi, 0, 1, 2, 3, 4, 5, 6, 7);
}
__device__ __forceinline__ void gload16(const void* g, void* l) {
    __builtin_amdgcn_global_load_lds(
        (const __attribute__((address_space(1))) void*)g,
        (__attribute__((address_space(3))) void*)l, 16, 0, 0);
}

// ---------------------------------------------------------------------------
// Fused f32->bf16 convert for 4 regions (x, Wqd, Wkvd, Wqu).
// ---------------------------------------------------------------------------
__global__ __launch_bounds__(256) void cvt4_k(
    const float* __restrict__ x, const float* __restrict__ wqd,
    const float* __restrict__ wkvd, const float* __restrict__ wqu,
    u16* __restrict__ xb, u16* __restrict__ wqdb,
    u16* __restrict__ wkvdb, u16* __restrict__ wqub)
{
    const int total = 4358144;
    int i = blockIdx.x * 256 + threadIdx.x;
    const int stride = gridDim.x * 256;
    for (; i < total; i += stride) {
        const float4* src; ushort4* dst; int off;
        if (i < 2097152)      { src = (const float4*)x;    dst = (ushort4*)xb;    off = i; }
        else if (i < 2883584) { src = (const float4*)wqd;  dst = (ushort4*)wqdb;  off = i - 2097152; }
        else if (i < 3178496) { src = (const float4*)wkvd; dst = (ushort4*)wkvdb; off = i - 2883584; }
        else                  { src = (const float4*)wqu;  dst = (ushort4*)wqub;  off = i - 3178496; }
        float4 v = src[off];
        ushort4 o = { f2b(v.x), f2b(v.y), f2b(v.z), f2b(v.w) };
        dst[off] = o;
    }
}

__global__ __launch_bounds__(256) void cvt_bf16_k(
    const float* __restrict__ in, u16* __restrict__ out, int n4)
{
    int i = blockIdx.x * 256 + threadIdx.x;
    const int stride = gridDim.x * 256;
    for (; i < n4; i += stride) {
        float4 v = ((const float4*)in)[i];
        ushort4 o = { f2b(v.x), f2b(v.y), f2b(v.z), f2b(v.w) };
        ((ushort4*)out)[i] = o;
    }
}

// ---------------------------------------------------------------------------
// 8-phase GEMM (T2+T3+T4+T5), verified R20-R24. TM=256 or 128. bf16 A.
// MODE: 0 bf16-out | 1 f32-out | 2 qup(rope+QS) | 3 down(dual-dest)
// ---------------------------------------------------------------------------
template <int MODE, int TM>
__global__ __launch_bounds__(512, 2) void gemm8p_k(
    const u16* __restrict__ A, const u16* __restrict__ W0,
    const u16* __restrict__ W1, const float* __restrict__ b0,
    const float* __restrict__ b1, void* __restrict__ C0, void* __restrict__ C1,
    int N, int K, int lda,
    const float* __restrict__ fc, const float* __restrict__ fs)
{
    constexpr int AH  = TM / 128;
    constexpr int MPP = TM == 256 ? 2 : 1;
    __shared__ u16 lsA[2][AH][128 * 64];
    __shared__ u16 lsB[2][2][128 * 64];
    const int tid  = threadIdx.x;
    const int lane = tid & 63;
    const int w    = tid >> 6;
    const int wm   = w >> 2;
    const int wn   = w & 3;
    const int row0 = blockIdx.y * TM;
    const int col0 = blockIdx.x * 256;
    const int nt   = K / 64;

    auto stageA = [&](int t, int h) {
        const int kt = t * 64, buf = t & 1;
#pragma unroll
        for (int j = 0; j < 2; j++) {
            const int g = (w * 2 + j) * 64 + lane;
            const int row = g >> 3, c16 = g & 7;
            const int cs = c16 ^ (row & 7);
            gload16(A + (size_t)(row0 + h * 128 + row) * lda + kt + cs * 8,
                    &lsA[buf][h][(w * 2 + j) * 512]);
        }
    };
    auto stageB = [&](int t, int h) {
        const int kt = t * 64, buf = t & 1;
#pragma unroll
        for (int j = 0; j < 2; j++) {
            const int g = (w * 2 + j) * 64 + lane;
            const int row = g >> 3, c16 = g & 7;
            const int cs = c16 ^ (row & 7);
            int rw = col0 + h * 128 + row;
            const u16* Wp;
            if (MODE == 3) {
                const bool in1 = rw >= 1536;
                int r2 = in1 ? rw - 1536 : rw;
                if (in1 && r2 > 575) r2 = 575;
                Wp = (in1 ? W1 : W0) + (size_t)r2 * K;
            } else {
                if (rw >= N) rw = N - 1;
                Wp = W0 + (size_t)rw * K;
            }
            gload16(Wp + kt + cs * 8, &lsB[buf][h][(w * 2 + j) * 512]);
        }
    };
    auto readA = [&](int buf, int mf, int kh) -> s16x8 {
        const int h  = TM == 256 ? wm : 0;
        const int ra = (TM == 256 ? mf * 16 : wm * 64 + mf * 16) + (lane & 15);
        const int c16 = kh * 4 + (lane >> 4);
        return *(const s16x8*)&lsA[buf][h][(ra * 8 + (c16 ^ (ra & 7))) * 8];
    };
    auto readB = [&](int buf, int nf, int kh) -> s16x8 {
        const int rb = (wn & 1) * 64 + nf * 16 + (lane & 15);
        const int c16 = kh * 4 + (lane >> 4);
        return *(const s16x8*)&lsB[buf][wn >> 1][(rb * 8 + (c16 ^ (rb & 7))) * 8];
    };

    f32x4 acc[4 * MPP][4];
#pragma unroll
    for (int i = 0; i < 4 * MPP; i++)
#pragma unroll
        for (int j = 0; j < 4; j++) acc[i][j] = (f32x4){0.f, 0.f, 0.f, 0.f};

    stageB(0, 0); stageB(0, 1);
#pragma unroll
    for (int h = 0; h < AH; h++) stageA(0, h);
    stageB(1, 0); stageB(1, 1);
    asm volatile("s_waitcnt vmcnt(4)" ::: "memory");
    asm volatile("s_barrier" ::: "memory");

    for (int t = 0; t < nt; t++) {
        const int buf = t & 1;
        s16x8 bfr[4][2];
#pragma unroll
        for (int nf = 0; nf < 4; nf++)
#pragma unroll
            for (int kh = 0; kh < 2; kh++) bfr[nf][kh] = readB(buf, nf, kh);
#pragma unroll
        for (int ph = 0; ph < 4; ph++) {
            s16x8 af[MPP][2];
#pragma unroll
            for (int m2 = 0; m2 < MPP; m2++)
#pragma unroll
                for (int kh = 0; kh < 2; kh++)
                    af[m2][kh] = readA(buf, ph * MPP + m2, kh);
            if (ph == 0) { if (t + 1 < nt) stageA(t + 1, 0); }
            else if (ph == 1) {
                if (TM == 256) { if (t + 1 < nt) stageA(t + 1, 1); }
                if (t + 2 < nt) stageB(t + 2, 0);
            } else if (ph == 2) { if (t + 2 < nt) stageB(t + 2, 1); }
            __builtin_amdgcn_s_setprio(1);
#pragma unroll
            for (int kh = 0; kh < 2; kh++)
#pragma unroll
                for (int m2 = 0; m2 < MPP; m2++)
#pragma unroll
                    for (int nf = 0; nf < 4; nf++)
                        acc[ph * MPP + m2][nf] = __builtin_amdgcn_mfma_f32_16x16x32_bf16(
                            af[m2][kh], bfr[nf][kh], acc[ph * MPP + m2][nf], 0, 0, 0);
            __builtin_amdgcn_s_setprio(0);
            if (ph == 0) asm volatile("s_barrier" ::: "memory");
        }
        if (t + 2 < nt) asm volatile("s_waitcnt vmcnt(4)" ::: "memory");
        else            asm volatile("s_waitcnt vmcnt(0)" ::: "memory");
        asm volatile("s_barrier" ::: "memory");
    }

    const float QS = 0.10411754f;  // 192^-0.5 * log2(e)
    const int rbase = row0 + wm * (TM == 256 ? 128 : 64) + ((lane >> 4) << 2);
    const int cbase = col0 + wn * 64 + (lane & 15);
#pragma unroll
    for (int nf = 0; nf < 4; nf++) {
        const int col = cbase + nf * 16;
        if (MODE == 3) {
            if (col < 2112) {
                const bool c1 = col >= 1536;
                const float bv = c1 ? b1[col - 1536] : b0[col];
#pragma unroll
                for (int mf = 0; mf < 4 * MPP; mf++)
#pragma unroll
                    for (int r = 0; r < 4; r++) {
                        const int row = rbase + mf * 16 + r;
                        const float v = acc[mf][nf][r] + bv;
                        if (c1) ((u16*)C1)[(size_t)row * 576 + col - 1536] = f2b_hw(v);
                        else    ((u16*)C0)[(size_t)row * 1536 + col] = f2b_hw(v);
                    }
            }
        } else if (MODE == 2) {
            const float bv = b0[col];
            const int colBase = col0 + wn * 64 + nf * 16;
            const int dh0 = colBase % 192;
            const bool ropeBlk = (dh0 >= 128);
            const int ib = (dh0 - 128 + (lane & 15)) >> 1;
#pragma unroll
            for (int mf = 0; mf < 4 * MPP; mf++)
#pragma unroll
                for (int r = 0; r < 4; r++) {
                    const int row = rbase + mf * 16 + r;
                    float v = acc[mf][nf][r] + bv;
                    if (ropeBlk) {
                        const float pp = __shfl_xor(v, 1);
                        const int s = row & (SEQ - 1);
                        const float c = fc[s * 32 + ib], sn = fs[s * 32 + ib];
                        v = (lane & 1) ? (v * c + pp * sn) : (v * c - pp * sn);
                    }
                    ((u16*)C0)[(size_t)row * 3072 + col] = f2b_hw(v * QS);
                }
        } else {
            if (col < N) {
                const float bv = b0[col];
#pragma unroll
                for (int mf = 0; mf < 4 * MPP; mf++)
#pragma unroll
                    for (int r = 0; r < 4; r++) {
                        const int row = rbase + mf * 16 + r;
                        const float v = acc[mf][nf][r] + bv;
                        if (MODE == 1) ((float*)C0)[(size_t)row * N + col] = v;
                        else           ((u16*)C0)[(size_t)row * N + col] = f2b_hw(v);
                    }
            }
        }
    }
}

// ---------------------------------------------------------------------------
// Merged RMSNorm (qlat + kvb) + rope_k — vectorized.
// ---------------------------------------------------------------------------
__global__ __launch_bounds__(256) void norm_rope_k(
    u16* __restrict__ qlat, u16* __restrict__ kvb,
    const float* __restrict__ qnw, const float* __restrict__ kvnw,
    const float* __restrict__ fc, const float* __restrict__ fs,
    u16* __restrict__ krope)
{
    const int bid = blockIdx.x;
    const int row = bid & 4095;
    const bool isq = bid < 4096;
    u16* xr = isq ? qlat + (size_t)row * 1536 : kvb + (size_t)row * 576;
    const int cols = isq ? 1536 : 512;
    const float* wv = isq ? qnw : kvnw;
    const int t = threadIdx.x;
    const int nv = cols >> 3;

    if (!isq && t < 32) {
        const int i = t;
        const int s = row & (SEQ - 1);
        const u16* src = kvb + (size_t)row * 576 + 512 + 2 * i;
        const float xr0 = b2f(src[0]), xi0 = b2f(src[1]);
        const float c = fc[s * 32 + i], sn = fs[s * 32 + i];
        ushort2 o;
        o.x = f2b(xr0 * c - xi0 * sn);
        o.y = f2b(xr0 * sn + xi0 * c);
        *((ushort2*)(krope + (size_t)row * 64) + i) = o;
    }

    s16x8 v = {0,0,0,0,0,0,0,0};
    float ss = 0.f;
    if (t < nv) {
        v = *(const s16x8*)(xr + t * 8);
#pragma unroll
        for (int e = 0; e < 8; e++) { float f = b2f((u16)v[e]); ss += f * f; }
    }
#pragma unroll
    for (int off = 32; off; off >>= 1) ss += __shfl_xor(ss, off);
    __shared__ float red[4];
    if ((t & 63) == 0) red[t >> 6] = ss;
    __syncthreads();
    const float tot = red[0] + red[1] + red[2] + red[3];
    const float inv = rsqrtf(tot / (float)cols + 1.1920929e-7f);
    if (t < nv) {
        s16x8 o;
#pragma unroll
        for (int e = 0; e < 8; e++)
            o[e] = (short)f2b(b2f((u16)v[e]) * inv * wv[t * 8 + e]);
        *(s16x8*)(xr + t * 8) = o;
    }
}

// ---------------------------------------------------------------------------
// MFMA flash attention v11 (R24 proven state: stride-204 k_lds, masked-tile
// skip, exp2 softmax, native casts; NO setprio, prefetch AFTER barrier —
// R26's v12 variants regressed 116.5 -> 125 µs).
// ---------------------------------------------------------------------------
__global__ __launch_bounds__(256, 2) void attn_k(
    const u16* __restrict__ Q, const u16* __restrict__ KNV,
    const u16* __restrict__ KR, u16* __restrict__ O)
{
    __shared__ u16 k_lds[64][204];
    __shared__ u16 v_t[128][76];

    const int tid  = threadIdx.x;
    const int lane = tid & 63;
    const int w    = tid >> 6;
    const int lr   = lane & 15;
    const int lq   = lane >> 4;

    const int bid = blockIdx.x;
    const int qt  = (bid < 256) ? (15 - (bid >> 5)) : ((bid - 256) >> 5);
    const int bh  = bid & 31;
    const int h   = bh & 15;
    const int b   = bh >> 4;
    const int q0  = qt * 128;
    const int bS  = b * SEQ;

    s16x8 qf[2][6];
#pragma unroll
    for (int mb = 0; mb < 2; mb++) {
        const u16* qp = Q + (size_t)(bS + q0 + w * 32 + mb * 16 + lr) * 3072
                        + h * 192 + (lq << 2);
#pragma unroll
        for (int kc = 0; kc < 6; kc++)
            qf[mb][kc] = comb(*(const s16x4*)(qp + kc * 32),
                              *(const s16x4*)(qp + kc * 32 + 16));
    }

    f32x4 o_acc[2][8];
#pragma unroll
    for (int mb = 0; mb < 2; mb++)
#pragma unroll
        for (int d = 0; d < 8; d++) o_acc[mb][d] = (f32x4){0.f, 0.f, 0.f, 0.f};
    float m_run[2] = { -1e30f, -1e30f };
    float l_run[2] = { 0.f, 0.f };

    const int ntiles = (q0 + 128) / 64;
    const int qmax_w = q0 + w * 32 + 31;

    s16x8 kr[6], vr[4];
    const int kkey = tid >> 2;
    const int ka   = tid & 3;

    {
        const u16* kn  = KNV + (size_t)(bS + kkey) * 4096 + h * 256;
        const u16* krp = KR + (size_t)(bS + kkey) * 64;
#pragma unroll
        for (int i = 0; i < 6; i++) {
            const int col = ka * 48 + i * 8;
            kr[i] = *(const s16x8*)(col < 128 ? kn + col : krp + (col - 128));
        }
#pragma unroll
        for (int i = 0; i < 4; i++) {
            const int idx = tid + i * 256;
            vr[i] = *(const s16x8*)(KNV + (size_t)(bS + (idx >> 4)) * 4096
                                    + h * 256 + 128 + (idx & 15) * 8);
        }
    }

    for (int t = 0; t < ntiles; t++) {
#pragma unroll
        for (int i = 0; i < 6; i++) {
            const int c0 = ka * 48 + i * 8;
            *(s16x4*)&k_lds[kkey][c0]     = __builtin_shufflevector(kr[i], kr[i], 0, 1, 2, 3);
            *(s16x4*)&k_lds[kkey][c0 + 4] = __builtin_shufflevector(kr[i], kr[i], 4, 5, 6, 7);
        }
#pragma unroll
        for (int i = 0; i < 4; i++) {
            const int idx = tid + i * 256;
            const int key = idx >> 4, d0 = (idx & 15) * 8;
            const int xw = (d0 >> 4) << 2;
#pragma unroll
            for (int e = 0; e < 8; e++) v_t[d0 + e][key ^ xw] = (u16)vr[i][e];
        }
        __syncthreads();

        if (t + 1 < ntiles) {
            const int nk = (t + 1) * 64;
            const u16* kn  = KNV + (size_t)(bS + nk + kkey) * 4096 + h * 256;
            const u16* krp = KR + (size_t)(bS + nk + kkey) * 64;
#pragma unroll
            for (int i = 0; i < 6; i++) {
                const int col = ka * 48 + i * 8;
                kr[i] = *(const s16x8*)(col < 128 ? kn + col : krp + (col - 128));
            }
#pragma unroll
            for (int i = 0; i < 4; i++) {
                const int idx = tid + i * 256;
                vr[i] = *(const s16x8*)(KNV + (size_t)(bS + nk + (idx >> 4)) * 4096
                                        + h * 256 + 128 + (idx & 15) * 8);
            }
        }

        const int kt0 = t * 64;
        if (kt0 <= qmax_w) {
            f32x4 sa[2][4];
#pragma unroll
            for (int mb = 0; mb < 2; mb++)
#pragma unroll
                for (int f = 0; f < 4; f++) sa[mb][f] = (f32x4){0.f, 0.f, 0.f, 0.f};
#pragma unroll
            for (int kc = 0; kc < 6; kc++) {
                const int kb = kc * 32 + (lq << 2);
#pragma unroll
                for (int f = 0; f < 4; f++) {
                    s16x8 kf = comb(*(const s16x4*)&k_lds[f * 16 + lr][kb],
                                    *(const s16x4*)&k_lds[f * 16 + lr][kb + 16]);
                    sa[0][f] = __builtin_amdgcn_mfma_f32_16x16x32_bf16(kf, qf[0][kc], sa[0][f], 0, 0, 0);
                    sa[1][f] = __builtin_amdgcn_mfma_f32_16x16x32_bf16(kf, qf[1][kc], sa[1][f], 0, 0, 0);
                }
            }

            s16x8 pb[2][2];
#pragma unroll
            for (int mb = 0; mb < 2; mb++) {
                const int qrow = q0 + w * 32 + mb * 16 + lr;
                const bool need_mask = (kt0 + 63 > qrow);
                float p[4][4];
#pragma unroll
                for (int f = 0; f < 4; f++)
#pragma unroll
                    for (int r = 0; r < 4; r++) {
                        float s = sa[mb][f][r];
                        if (need_mask && (kt0 + f * 16 + lq * 4 + r > qrow)) s = -1e30f;
                        p[f][r] = s;
                    }
                float tm = p[0][0];
#pragma unroll
                for (int f = 0; f < 4; f++)
#pragma unroll
                    for (int r = 0; r < 4; r++) tm = fmaxf(tm, p[f][r]);
                tm = fmaxf(tm, __shfl_xor(tm, 16));
                tm = fmaxf(tm, __shfl_xor(tm, 32));

                const float mo = m_run[mb];
                const bool keep = __all(tm <= mo + 8.f);
                float corr = 1.f;
                if (!keep) {
                    const float nm = fmaxf(mo, tm);
                    corr = __builtin_amdgcn_exp2f(mo - nm);
                    m_run[mb] = nm;
                }
                const float mbase = m_run[mb];
#pragma unroll
                for (int f = 0; f < 4; f++)
#pragma unroll
                    for (int r = 0; r < 4; r++)
                        p[f][r] = __builtin_amdgcn_exp2f(p[f][r] - mbase);
                float ps = 0.f;
#pragma unroll
                for (int f = 0; f < 4; f++)
#pragma unroll
                    for (int r = 0; r < 4; r++) ps += p[f][r];
                ps += __shfl_xor(ps, 16);
                ps += __shfl_xor(ps, 32);
                l_run[mb] = l_run[mb] * corr + ps;
                if (!keep) {
#pragma unroll
                    for (int d = 0; d < 8; d++)
#pragma unroll
                        for (int r = 0; r < 4; r++) o_acc[mb][d][r] *= corr;
                }
#pragma unroll
                for (int hf = 0; hf < 2; hf++) {
                    s16x8 v;
#pragma unroll
                    for (int j = 0; j < 8; j++)
                        v[j] = (short)f2b_hw(p[hf * 2 + (j >> 2)][j & 3]);
                    pb[mb][hf] = v;
                }
            }

#pragma unroll
            for (int hf = 0; hf < 2; hf++) {
                const int pc = hf * 32 + (lq << 2);
#pragma unroll
                for (int df = 0; df < 8; df++) {
                    const int row = df * 16 + lr;
                    const int xr0 = df << 2;
                    s16x8 vf = comb(*(const s16x4*)&v_t[row][pc ^ xr0],
                                    *(const s16x4*)&v_t[row][(pc + 16) ^ xr0]);
                    o_acc[0][df] = __builtin_amdgcn_mfma_f32_16x16x32_bf16(vf, pb[0][hf], o_acc[0][df], 0, 0, 0);
                    o_acc[1][df] = __builtin_amdgcn_mfma_f32_16x16x32_bf16(vf, pb[1][hf], o_acc[1][df], 0, 0, 0);
                }
            }
        }
        __syncthreads();
    }

#pragma unroll
    for (int mb = 0; mb < 2; mb++) {
        const float invl = 1.f / l_run[mb];
        u16* op = O + (size_t)(bS + q0 + w * 32 + mb * 16 + lr) * 2048 + h * 128 + lq * 4;
#pragma unroll
        for (int df = 0; df < 8; df++) {
            ushort4 ov = { f2b_hw(o_acc[mb][df][0] * invl), f2b_hw(o_acc[mb][df][1] * invl),
                           f2b_hw(o_acc[mb][df][2] * invl), f2b_hw(o_acc[mb][df][3] * invl) };
            *(ushort4*)(op + df * 16) = ov;
        }
    }
}

// ---------------------------------------------------------------------------
extern "C" void kernel_launch(void* const* d_in, const int* in_sizes, int n_in,
                              void* d_out, int out_size, void* d_ws, size_t ws_size,
                              hipStream_t stream)
{
    const float* x    = (const float*)d_in[0];
    const float* fc   = (const float*)d_in[1];
    const float* fs   = (const float*)d_in[2];
    const float* Wqd  = (const float*)d_in[3];
    const float* bqd  = (const float*)d_in[4];
    const float* qnw  = (const float*)d_in[5];
    const float* Wqu  = (const float*)d_in[6];
    const float* bqu  = (const float*)d_in[7];
    const float* Wkvd = (const float*)d_in[8];
    const float* bkvd = (const float*)d_in[9];
    const float* kvnw = (const float*)d_in[10];
    const float* Wkvu = (const float*)d_in[11];
    const float* bkvu = (const float*)d_in[12];
    const float* Wo   = (const float*)d_in[13];
    const float* bo   = (const float*)d_in[14];

    char* ws = (char*)d_ws;
    // Lifetime-audited layout (R24, proven):
    u16* kvb     = (u16*)(ws);                 // [4096][576]  live: down..kvup
    u16* qlat    = (u16*)(ws + 4718592);       // [4096][1536] live: down..qup
    u16* qbuf    = (u16*)(ws + 17301504);      // [4096][3072] live: qup..attn
    u16* krope   = (u16*)(ws + 42467328);      // [4096][64]   live: norm..attn
    u16* knv     = (u16*)(ws + 42991616);      // [4096][4096] live: kvup..attn
    u16* attn_o  = (u16*)(ws);                 // [4096][2048] live: attn..out
    u16* x_bf    = (u16*)(ws + 17301504);      // in qbuf slot, dead before qup
    u16* wqd_bf  = (u16*)(ws + 42991616);      // in knv slot, dead before kvup
    u16* wkvd_bf = (u16*)(ws + 49283072);      //   "
    u16* wqu_bf  = (u16*)(ws + 51642368);      //   "  (qup runs BEFORE kvup)
    u16* wkvu_bf = (u16*)(ws + 4718592);       // in qlat slot, converted after qup
    u16* wo_bf   = (u16*)(ws + 42991616);      // in knv slot, knv dead after attn

    cvt4_k<<<2048, 256, 0, stream>>>(x, Wqd, Wkvd, Wqu, x_bf, wqd_bf, wkvd_bf, wqu_bf);
    gemm8p_k<3, 256><<<dim3(9, 16), 512, 0, stream>>>(
        x_bf, wqd_bf, wkvd_bf, bqd, bkvd, qlat, kvb, 2112, 2048, 2048, nullptr, nullptr);
    norm_rope_k<<<8192, 256, 0, stream>>>(qlat, kvb, qnw, kvnw, fc, fs, krope);
    gemm8p_k<2, 256><<<dim3(12, 16), 512, 0, stream>>>(
        qlat, wqu_bf, nullptr, bqu, nullptr, qbuf, nullptr, 3072, 1536, 1536, fc, fs);
    cvt_bf16_k<<<1024, 256, 0, stream>>>(Wkvu, wkvu_bf, 2097152 / 4);
    gemm8p_k<0, 256><<<dim3(16, 16), 512, 0, stream>>>(
        kvb, wkvu_bf, nullptr, bkvu, nullptr, knv, nullptr, 4096, 512, 576, nullptr, nullptr);
    attn_k<<<512, 256, 0, stream>>>(qbuf, knv, krope, attn_o);
    cvt_bf16_k<<<1024, 256, 0, stream>>>(Wo, wo_bf, 4194304 / 4);
    gemm8p_k<1, 128><<<dim3(8, 32), 512, 0, stream>>>(
        attn_o, wo_bf, nullptr, bo, nullptr, d_out, nullptr, 2048, 2048, 2048, nullptr, nullptr);
}